// Round 5
// baseline (134.319 us; speedup 1.0000x reference)
//
#include <hip/hip_runtime.h>

#define DIMSZ 300
#define CCH   16
#define NPTS  1048576

typedef _Float16 half4 __attribute__((ext_vector_type(4)));
typedef float    fvec4 __attribute__((ext_vector_type(4)));
typedef float    fvec2 __attribute__((ext_vector_type(2)));

__device__ __forceinline__ fvec4 h2f(half4 h) {
    fvec4 r;
    r.x = (float)h[0]; r.y = (float)h[1]; r.z = (float)h[2]; r.w = (float)h[3];
    return r;
}

// ---------------------------------------------------------------------------
// Planes: (C, HW) f32  ->  (HW, C) fp16.  blockIdx.y selects which plane.
// ---------------------------------------------------------------------------
__global__ __launch_bounds__(256) void transpose_planes(
    const float* __restrict__ a, const float* __restrict__ b, const float* __restrict__ c,
    _Float16* __restrict__ ta, _Float16* __restrict__ tb, _Float16* __restrict__ tc)
{
    const int HW = DIMSZ * DIMSZ;
    const float* in  = (blockIdx.y == 0) ? a  : (blockIdx.y == 1) ? b  : c;
    _Float16*    out = (blockIdx.y == 0) ? ta : (blockIdx.y == 1) ? tb : tc;

    __shared__ float tile[64][CCH + 1];
    int pix0 = blockIdx.x * 64;
    int t = threadIdx.x;

    int p  = t & 63;
    int cg = t >> 6;   // 0..3
#pragma unroll
    for (int k = 0; k < 4; ++k) {
        int ch  = cg * 4 + k;
        int pix = pix0 + p;
        tile[p][ch] = (pix < HW) ? __builtin_nontemporal_load(&in[(size_t)ch * HW + pix]) : 0.f;
    }
    __syncthreads();

    int q  = t & 3;
    int pr = t >> 2;   // 0..63
    int pix = pix0 + pr;
    if (pix < HW) {
        half4 h;
        h[0] = (_Float16)tile[pr][q * 4 + 0];
        h[1] = (_Float16)tile[pr][q * 4 + 1];
        h[2] = (_Float16)tile[pr][q * 4 + 2];
        h[3] = (_Float16)tile[pr][q * 4 + 3];
        ((half4*)out)[(size_t)pix * 4 + q] = h;
    }
}

// ---------------------------------------------------------------------------
// Lines: (C, H) f32 -> (H, C) f32.  Tiny.
// ---------------------------------------------------------------------------
__global__ __launch_bounds__(256) void transpose_lines(
    const float* __restrict__ a, const float* __restrict__ b, const float* __restrict__ c,
    float* __restrict__ ta, float* __restrict__ tb, float* __restrict__ tc)
{
    const float* in  = (blockIdx.y == 0) ? a  : (blockIdx.y == 1) ? b  : c;
    float*       out = (blockIdx.y == 0) ? ta : (blockIdx.y == 1) ? tb : tc;
    for (int idx = threadIdx.x; idx < DIMSZ * CCH; idx += 256) {
        int p  = idx >> 4;
        int ch = idx & 15;
        out[idx] = in[ch * DIMSZ + p];
    }
}

// ---------------------------------------------------------------------------
// Per-plane main kernel, 2 samples per thread (MLP).
// K = output slot (0: yz*x, 1: xz*y, 2: xy*z).
// ---------------------------------------------------------------------------
template <int K>
__global__ __launch_bounds__(256) void td_plane(
    const float* __restrict__ coords_plane,
    const float* __restrict__ coords_line,
    const _Float16* __restrict__ ptex,
    const float* __restrict__ ltex,
    float* __restrict__ out)
{
    int gid = blockIdx.x * 256 + threadIdx.x;   // [0, NPTS*2)
    int q  = gid & 3;
    int ip = gid >> 2;            // sample-pair index [0, NPTS/2)
    int i0 = ip * 2;
    if (i0 >= NPTS) return;

    // out_x uses plane coords slice 1 (yz), out_y slice 2 (xz), out_z slice 0 (xy)
    constexpr int PC = (K == 0) ? 1 : (K == 1) ? 2 : 0;

    // one 16-B load covers both samples' plane coords; same for line coords
    const fvec4* cp4 = (const fvec4*)coords_plane;
    const fvec4* cl4 = (const fvec4*)coords_line;
    fvec4 cpv = __builtin_nontemporal_load(&cp4[(size_t)PC * (NPTS / 2) + ip]);
    fvec4 clv = __builtin_nontemporal_load(&cl4[(size_t)K  * (NPTS / 2) + ip]);

    const half4* t4 = (const half4*)ptex;
    const fvec4* l4 = (const fvec4*)ltex;

    float gx[2] = {cpv.x, cpv.z};
    float gy[2] = {cpv.y, cpv.w};
    float gl[2] = {clv.y, clv.w};

    fvec4 res[2];

#pragma unroll
    for (int s = 0; s < 2; ++s) {
        // ---- plane bilinear (W = H = 300) ----
        float ix = (gx[s] + 1.f) * 0.5f * (float)(DIMSZ - 1);
        float iy = (gy[s] + 1.f) * 0.5f * (float)(DIMSZ - 1);
        float ix0f = floorf(ix), iy0f = floorf(iy);
        float wx = ix - ix0f, wy = iy - iy0f;
        int ix0 = min(max((int)ix0f, 0), DIMSZ - 1);
        int ix1 = min(ix0 + 1, DIMSZ - 1);
        int iy0 = min(max((int)iy0f, 0), DIMSZ - 1);
        int iy1 = min(iy0 + 1, DIMSZ - 1);

        size_t r0 = (size_t)iy0 * DIMSZ;
        size_t r1 = (size_t)iy1 * DIMSZ;
        fvec4 v00 = h2f(t4[(r0 + ix0) * 4 + q]);
        fvec4 v01 = h2f(t4[(r0 + ix1) * 4 + q]);
        fvec4 v10 = h2f(t4[(r1 + ix0) * 4 + q]);
        fvec4 v11 = h2f(t4[(r1 + ix1) * 4 + q]);

        float w00 = (1.f - wx) * (1.f - wy);
        float w01 = wx * (1.f - wy);
        float w10 = (1.f - wx) * wy;
        float w11 = wx * wy;

        fvec4 f = v00 * w00 + v01 * w01 + v10 * w10 + v11 * w11;

        // ---- line linear (H = 300) ----
        float lyv = (gl[s] + 1.f) * 0.5f * (float)(DIMSZ - 1);
        float ly0f = floorf(lyv);
        float wl = lyv - ly0f;
        int l0 = min(max((int)ly0f, 0), DIMSZ - 1);
        int l1 = min(l0 + 1, DIMSZ - 1);

        fvec4 u0 = l4[(size_t)l0 * 4 + q];
        fvec4 u1 = l4[(size_t)l1 * 4 + q];
        fvec4 fl = u0 * (1.f - wl) + u1 * wl;

        res[s] = f * fl;
    }

    fvec4* out4 = (fvec4*)out;
    size_t ob = (size_t)K * NPTS * 4 + (size_t)i0 * 4 + q;
    __builtin_nontemporal_store(res[0], &out4[ob]);
    __builtin_nontemporal_store(res[1], &out4[ob + 4]);
}

// ---------------------------------------------------------------------------
// Fallback (no usable ws): direct f32 gather from original (C,H,W) layout.
// ---------------------------------------------------------------------------
__global__ __launch_bounds__(256) void td_fallback(
    const float* __restrict__ coords_plane,
    const float* __restrict__ coords_line,
    const float* __restrict__ pxy, const float* __restrict__ pyz,
    const float* __restrict__ pxz,
    const float* __restrict__ lx, const float* __restrict__ ly,
    const float* __restrict__ lz,
    float* __restrict__ out)
{
    int gid = blockIdx.x * 256 + threadIdx.x;
    int i = gid >> 2;
    int q = gid & 3;
    if (i >= NPTS) return;

    const fvec2* cp = (const fvec2*)coords_plane;
    const fvec2* cl = (const fvec2*)coords_line;

    fvec4* out4 = (fvec4*)out;
    const float* planes[3] = {pyz, pxz, pxy};
    const float* lines[3]  = {lx, ly, lz};
    const int    pcs[3]    = {1, 2, 0};

#pragma unroll
    for (int k = 0; k < 3; ++k) {
        fvec2 g  = cp[(size_t)pcs[k] * NPTS + i];
        float gl = cl[(size_t)k * NPTS + i].y;

        float ix = (g.x + 1.f) * 0.5f * (float)(DIMSZ - 1);
        float iy = (g.y + 1.f) * 0.5f * (float)(DIMSZ - 1);
        float ix0f = floorf(ix), iy0f = floorf(iy);
        float wx = ix - ix0f, wy = iy - iy0f;
        int ix0 = min(max((int)ix0f, 0), DIMSZ - 1);
        int ix1 = min(ix0 + 1, DIMSZ - 1);
        int iy0 = min(max((int)iy0f, 0), DIMSZ - 1);
        int iy1 = min(iy0 + 1, DIMSZ - 1);
        float w00 = (1.f - wx) * (1.f - wy), w01 = wx * (1.f - wy);
        float w10 = (1.f - wx) * wy,         w11 = wx * wy;

        float lyv = (gl + 1.f) * 0.5f * (float)(DIMSZ - 1);
        float ly0f = floorf(lyv);
        float wl = lyv - ly0f;
        int l0 = min(max((int)ly0f, 0), DIMSZ - 1);
        int l1 = min(l0 + 1, DIMSZ - 1);

        const float* P = planes[k];
        const float* L = lines[k];
        size_t hw = (size_t)DIMSZ * DIMSZ;
        int b00 = iy0 * DIMSZ + ix0, b01 = iy0 * DIMSZ + ix1;
        int b10 = iy1 * DIMSZ + ix0, b11 = iy1 * DIMSZ + ix1;
        fvec4 r;
#pragma unroll
        for (int j = 0; j < 4; ++j) {
            size_t cb = (size_t)(q * 4 + j) * hw;
            float fp = P[cb + b00] * w00 + P[cb + b01] * w01 +
                       P[cb + b10] * w10 + P[cb + b11] * w11;
            size_t lb = (size_t)(q * 4 + j) * DIMSZ;
            float flv = L[lb + l0] * (1.f - wl) + L[lb + l1] * wl;
            r[j] = fp * flv;
        }
        out4[(size_t)k * NPTS * 4 + (size_t)i * 4 + q] = r;
    }
}

// ---------------------------------------------------------------------------
extern "C" void kernel_launch(void* const* d_in, const int* in_sizes, int n_in,
                              void* d_out, int out_size, void* d_ws, size_t ws_size,
                              hipStream_t stream)
{
    const float* coords_plane = (const float*)d_in[0];
    const float* coords_line  = (const float*)d_in[1];
    const float* pxy = (const float*)d_in[2];
    const float* pyz = (const float*)d_in[3];
    const float* pxz = (const float*)d_in[4];
    const float* lx  = (const float*)d_in[5];
    const float* ly  = (const float*)d_in[6];
    const float* lz  = (const float*)d_in[7];
    float* out = (float*)d_out;

    const size_t planeH = (size_t)DIMSZ * DIMSZ * CCH;         // halves per plane
    const size_t lineF  = (size_t)DIMSZ * CCH;                 // floats per line
    const size_t needBytes = 3 * planeH * sizeof(_Float16) + 3 * lineF * sizeof(float);

    if (ws_size >= needBytes) {
        char* w = (char*)d_ws;
        _Float16* txy = (_Float16*)w;
        _Float16* tyz = txy + planeH;
        _Float16* txz = tyz + planeH;
        float* tlx = (float*)(w + 3 * planeH * sizeof(_Float16));
        float* tly = tlx + lineF;
        float* tlz = tly + lineF;

        dim3 gp((DIMSZ * DIMSZ + 63) / 64, 3);
        transpose_planes<<<gp, 256, 0, stream>>>(pxy, pyz, pxz, txy, tyz, txz);
        dim3 gl(1, 3);
        transpose_lines<<<gl, 256, 0, stream>>>(lx, ly, lz, tlx, tly, tlz);

        // 2 samples per thread -> NPTS*2 threads per plane kernel
        const int blocks2 = (NPTS * 2 + 255) / 256;
        td_plane<0><<<blocks2, 256, 0, stream>>>(coords_plane, coords_line, tyz, tlx, out);
        td_plane<1><<<blocks2, 256, 0, stream>>>(coords_plane, coords_line, txz, tly, out);
        td_plane<2><<<blocks2, 256, 0, stream>>>(coords_plane, coords_line, txy, tlz, out);
    } else {
        const int blocks = (NPTS * 4 + 255) / 256;
        td_fallback<<<blocks, 256, 0, stream>>>(coords_plane, coords_line,
                                                pxy, pyz, pxz, lx, ly, lz, out);
    }
}

// Round 6
// 132.704 us; speedup vs baseline: 1.0122x; 1.0122x over previous
//
#include <hip/hip_runtime.h>

#define DIMSZ 300
#define CCH   16
#define NPTS  1048576
#define BLOCKS_PER_K 16384   // NPTS*4 / 256

typedef _Float16 half4 __attribute__((ext_vector_type(4)));
typedef float    fvec4 __attribute__((ext_vector_type(4)));
typedef float    fvec2 __attribute__((ext_vector_type(2)));

__device__ __forceinline__ fvec4 h2f(half4 h) {
    fvec4 r;
    r.x = (float)h[0]; r.y = (float)h[1]; r.z = (float)h[2]; r.w = (float)h[3];
    return r;
}

// ---------------------------------------------------------------------------
// Planes: (C, HW) f32  ->  (HW, C) fp16.  blockIdx.y selects which plane.
// ---------------------------------------------------------------------------
__global__ __launch_bounds__(256) void transpose_planes(
    const float* __restrict__ a, const float* __restrict__ b, const float* __restrict__ c,
    _Float16* __restrict__ ta, _Float16* __restrict__ tb, _Float16* __restrict__ tc)
{
    const int HW = DIMSZ * DIMSZ;
    const float* in  = (blockIdx.y == 0) ? a  : (blockIdx.y == 1) ? b  : c;
    _Float16*    out = (blockIdx.y == 0) ? ta : (blockIdx.y == 1) ? tb : tc;

    __shared__ float tile[64][CCH + 1];
    int pix0 = blockIdx.x * 64;
    int t = threadIdx.x;

    int p  = t & 63;
    int cg = t >> 6;   // 0..3
#pragma unroll
    for (int k = 0; k < 4; ++k) {
        int ch  = cg * 4 + k;
        int pix = pix0 + p;
        tile[p][ch] = (pix < HW) ? in[(size_t)ch * HW + pix] : 0.f;
    }
    __syncthreads();

    int q  = t & 3;
    int pr = t >> 2;   // 0..63
    int pix = pix0 + pr;
    if (pix < HW) {
        half4 h;
        h[0] = (_Float16)tile[pr][q * 4 + 0];
        h[1] = (_Float16)tile[pr][q * 4 + 1];
        h[2] = (_Float16)tile[pr][q * 4 + 2];
        h[3] = (_Float16)tile[pr][q * 4 + 3];
        ((half4*)out)[(size_t)pix * 4 + q] = h;
    }
}

// ---------------------------------------------------------------------------
// Lines: (C, H) f32 -> (H, C) f32.  Tiny.
// ---------------------------------------------------------------------------
__global__ __launch_bounds__(256) void transpose_lines(
    const float* __restrict__ a, const float* __restrict__ b, const float* __restrict__ c,
    float* __restrict__ ta, float* __restrict__ tb, float* __restrict__ tc)
{
    const float* in  = (blockIdx.y == 0) ? a  : (blockIdx.y == 1) ? b  : c;
    float*       out = (blockIdx.y == 0) ? ta : (blockIdx.y == 1) ? tb : tc;
    for (int idx = threadIdx.x; idx < DIMSZ * CCH; idx += 256) {
        int p  = idx >> 4;
        int ch = idx & 15;
        out[idx] = in[ch * DIMSZ + p];
    }
}

// ---------------------------------------------------------------------------
// Fused main kernel: grid = 3 * BLOCKS_PER_K blocks; K = blockIdx.x >> 14,
// so all blocks of one K (one plane) dispatch before the next K begins ->
// per-XCD L2 holds one 2.88 MB fp16 plane at a time.
// Line texture (19.2 KB) is staged in LDS; its reads leave the global path.
// One thread per (sample, channel-quad).
// ---------------------------------------------------------------------------
__global__ __launch_bounds__(256) void td_all(
    const float* __restrict__ coords_plane,
    const float* __restrict__ coords_line,
    const _Float16* __restrict__ tyz, const _Float16* __restrict__ txz,
    const _Float16* __restrict__ txy,
    const float* __restrict__ tlx, const float* __restrict__ tly,
    const float* __restrict__ tlz,
    float* __restrict__ out)
{
    const int K = blockIdx.x >> 14;           // 0,1,2
    const int b = blockIdx.x & (BLOCKS_PER_K - 1);

    const _Float16* ptex = (K == 0) ? tyz : (K == 1) ? txz : txy;
    const float*    ltex = (K == 0) ? tlx : (K == 1) ? tly : tlz;
    const int PC = (K == 0) ? 1 : (K == 1) ? 2 : 0;   // plane-coord slice

    // ---- stage line texture (300 rows x 16 ch x 4 B = 19200 B) into LDS ----
    __shared__ fvec4 lline[DIMSZ * 4];        // [row*4 + quad]
    {
        const fvec4* l4 = (const fvec4*)ltex;
        for (int idx = threadIdx.x; idx < DIMSZ * 4; idx += 256)
            lline[idx] = l4[idx];
    }
    __syncthreads();

    int gid = b * 256 + threadIdx.x;
    int i = gid >> 2;
    int q = gid & 3;

    const fvec2* cp = (const fvec2*)coords_plane;
    const fvec2* cl = (const fvec2*)coords_line;
    fvec2 g   = cp[(size_t)PC * NPTS + i];
    float gl  = cl[(size_t)K * NPTS + i].y;   // lines use grid[:,1] (W==1)

    // ---- plane bilinear (W = H = 300) ----
    float ix = (g.x + 1.f) * 0.5f * (float)(DIMSZ - 1);
    float iy = (g.y + 1.f) * 0.5f * (float)(DIMSZ - 1);
    float ix0f = floorf(ix), iy0f = floorf(iy);
    float wx = ix - ix0f, wy = iy - iy0f;
    int ix0 = min(max((int)ix0f, 0), DIMSZ - 1);
    int ix1 = min(ix0 + 1, DIMSZ - 1);
    int iy0 = min(max((int)iy0f, 0), DIMSZ - 1);
    int iy1 = min(iy0 + 1, DIMSZ - 1);

    const half4* t4 = (const half4*)ptex;
    size_t r0 = (size_t)iy0 * DIMSZ;
    size_t r1 = (size_t)iy1 * DIMSZ;
    fvec4 v00 = h2f(t4[(r0 + ix0) * 4 + q]);
    fvec4 v01 = h2f(t4[(r0 + ix1) * 4 + q]);
    fvec4 v10 = h2f(t4[(r1 + ix0) * 4 + q]);
    fvec4 v11 = h2f(t4[(r1 + ix1) * 4 + q]);

    float w00 = (1.f - wx) * (1.f - wy);
    float w01 = wx * (1.f - wy);
    float w10 = (1.f - wx) * wy;
    float w11 = wx * wy;

    fvec4 f = v00 * w00 + v01 * w01 + v10 * w10 + v11 * w11;

    // ---- line linear from LDS (H = 300) ----
    float lyv = (gl + 1.f) * 0.5f * (float)(DIMSZ - 1);
    float ly0f = floorf(lyv);
    float wl = lyv - ly0f;
    int l0 = min(max((int)ly0f, 0), DIMSZ - 1);
    int l1 = min(l0 + 1, DIMSZ - 1);

    fvec4 u0 = lline[l0 * 4 + q];
    fvec4 u1 = lline[l1 * 4 + q];
    fvec4 fl = u0 * (1.f - wl) + u1 * wl;

    fvec4* out4 = (fvec4*)out;
    out4[(size_t)K * NPTS * 4 + (size_t)i * 4 + q] = f * fl;
}

// ---------------------------------------------------------------------------
// Fallback (no usable ws): direct f32 gather from original (C,H,W) layout.
// ---------------------------------------------------------------------------
__global__ __launch_bounds__(256) void td_fallback(
    const float* __restrict__ coords_plane,
    const float* __restrict__ coords_line,
    const float* __restrict__ pxy, const float* __restrict__ pyz,
    const float* __restrict__ pxz,
    const float* __restrict__ lx, const float* __restrict__ ly,
    const float* __restrict__ lz,
    float* __restrict__ out)
{
    int gid = blockIdx.x * 256 + threadIdx.x;
    int i = gid >> 2;
    int q = gid & 3;
    if (i >= NPTS) return;

    const fvec2* cp = (const fvec2*)coords_plane;
    const fvec2* cl = (const fvec2*)coords_line;

    fvec4* out4 = (fvec4*)out;
    const float* planes[3] = {pyz, pxz, pxy};
    const float* lines[3]  = {lx, ly, lz};
    const int    pcs[3]    = {1, 2, 0};

#pragma unroll
    for (int k = 0; k < 3; ++k) {
        fvec2 g  = cp[(size_t)pcs[k] * NPTS + i];
        float gl = cl[(size_t)k * NPTS + i].y;

        float ix = (g.x + 1.f) * 0.5f * (float)(DIMSZ - 1);
        float iy = (g.y + 1.f) * 0.5f * (float)(DIMSZ - 1);
        float ix0f = floorf(ix), iy0f = floorf(iy);
        float wx = ix - ix0f, wy = iy - iy0f;
        int ix0 = min(max((int)ix0f, 0), DIMSZ - 1);
        int ix1 = min(ix0 + 1, DIMSZ - 1);
        int iy0 = min(max((int)iy0f, 0), DIMSZ - 1);
        int iy1 = min(iy0 + 1, DIMSZ - 1);
        float w00 = (1.f - wx) * (1.f - wy), w01 = wx * (1.f - wy);
        float w10 = (1.f - wx) * wy,         w11 = wx * wy;

        float lyv = (gl + 1.f) * 0.5f * (float)(DIMSZ - 1);
        float ly0f = floorf(lyv);
        float wl = lyv - ly0f;
        int l0 = min(max((int)ly0f, 0), DIMSZ - 1);
        int l1 = min(l0 + 1, DIMSZ - 1);

        const float* P = planes[k];
        const float* L = lines[k];
        size_t hw = (size_t)DIMSZ * DIMSZ;
        int b00 = iy0 * DIMSZ + ix0, b01 = iy0 * DIMSZ + ix1;
        int b10 = iy1 * DIMSZ + ix0, b11 = iy1 * DIMSZ + ix1;
        fvec4 r;
#pragma unroll
        for (int j = 0; j < 4; ++j) {
            size_t cb = (size_t)(q * 4 + j) * hw;
            float fp = P[cb + b00] * w00 + P[cb + b01] * w01 +
                       P[cb + b10] * w10 + P[cb + b11] * w11;
            size_t lb = (size_t)(q * 4 + j) * DIMSZ;
            float flv = L[lb + l0] * (1.f - wl) + L[lb + l1] * wl;
            r[j] = fp * flv;
        }
        out4[(size_t)k * NPTS * 4 + (size_t)i * 4 + q] = r;
    }
}

// ---------------------------------------------------------------------------
extern "C" void kernel_launch(void* const* d_in, const int* in_sizes, int n_in,
                              void* d_out, int out_size, void* d_ws, size_t ws_size,
                              hipStream_t stream)
{
    const float* coords_plane = (const float*)d_in[0];
    const float* coords_line  = (const float*)d_in[1];
    const float* pxy = (const float*)d_in[2];
    const float* pyz = (const float*)d_in[3];
    const float* pxz = (const float*)d_in[4];
    const float* lx  = (const float*)d_in[5];
    const float* ly  = (const float*)d_in[6];
    const float* lz  = (const float*)d_in[7];
    float* out = (float*)d_out;

    const size_t planeH = (size_t)DIMSZ * DIMSZ * CCH;         // halves per plane
    const size_t lineF  = (size_t)DIMSZ * CCH;                 // floats per line
    const size_t needBytes = 3 * planeH * sizeof(_Float16) + 3 * lineF * sizeof(float);

    if (ws_size >= needBytes) {
        char* w = (char*)d_ws;
        _Float16* txy = (_Float16*)w;
        _Float16* tyz = txy + planeH;
        _Float16* txz = tyz + planeH;
        float* tlx = (float*)(w + 3 * planeH * sizeof(_Float16));
        float* tly = tlx + lineF;
        float* tlz = tly + lineF;

        dim3 gp((DIMSZ * DIMSZ + 63) / 64, 3);
        transpose_planes<<<gp, 256, 0, stream>>>(pxy, pyz, pxz, txy, tyz, txz);
        dim3 gl(1, 3);
        transpose_lines<<<gl, 256, 0, stream>>>(lx, ly, lz, tlx, tly, tlz);

        td_all<<<3 * BLOCKS_PER_K, 256, 0, stream>>>(coords_plane, coords_line,
                                                     tyz, txz, txy, tlx, tly, tlz, out);
    } else {
        const int blocks = (NPTS * 4 + 255) / 256;
        td_fallback<<<blocks, 256, 0, stream>>>(coords_plane, coords_line,
                                                pxy, pyz, pxz, lx, ly, lz, out);
    }
}

// Round 7
// 132.568 us; speedup vs baseline: 1.0132x; 1.0010x over previous
//
#include <hip/hip_runtime.h>

#define DIMSZ 300
#define CCH   16
#define NPTS  1048576

typedef _Float16 half8 __attribute__((ext_vector_type(8)));
typedef float    fvec8 __attribute__((ext_vector_type(8)));
typedef float    fvec4 __attribute__((ext_vector_type(4)));
typedef float    fvec2 __attribute__((ext_vector_type(2)));

__device__ __forceinline__ fvec8 h2f8(half8 h) {
    fvec8 r;
#pragma unroll
    for (int j = 0; j < 8; ++j) r[j] = (float)h[j];
    return r;
}

// ---------------------------------------------------------------------------
// Planes: (C, HW) f32 -> replicated-pair fp16 records.
// Record r = (y*300 + x), x in [0,298]: 64 B = [pix(x) ch0-7 | pix(x) ch8-15 |
// pix(x+1) ch0-7 | pix(x+1) ch8-15]  (4 half8 chunks).
// Pixel p contributes chunk h of record p (x<=298) and chunk 2+h of record p-1
// (x>=1). blockIdx.y selects plane.
// ---------------------------------------------------------------------------
__global__ __launch_bounds__(256) void transpose_planes(
    const float* __restrict__ a, const float* __restrict__ b, const float* __restrict__ c,
    _Float16* __restrict__ ta, _Float16* __restrict__ tb, _Float16* __restrict__ tc)
{
    const int HW = DIMSZ * DIMSZ;
    const float* in  = (blockIdx.y == 0) ? a  : (blockIdx.y == 1) ? b  : c;
    _Float16*    out = (blockIdx.y == 0) ? ta : (blockIdx.y == 1) ? tb : tc;

    __shared__ float tile[64][CCH + 1];
    int pix0 = blockIdx.x * 64;
    int t = threadIdx.x;

    // read: 64 pixels x 16 channels, coalesced along pixels
    int p  = t & 63;
    int cg = t >> 6;   // 0..3
#pragma unroll
    for (int k = 0; k < 4; ++k) {
        int ch  = cg * 4 + k;
        int pix = pix0 + p;
        tile[p][ch] = (pix < HW) ? in[(size_t)ch * HW + pix] : 0.f;
    }
    __syncthreads();

    // write: thread t -> (pixel pr, q). q = (role<<1)|h : h = channel half,
    // role 0 -> record p chunk h ; role 1 -> record p-1 chunk 2+h.
    int q    = t & 3;
    int h    = q & 1;
    int role = q >> 1;
    int pr   = t >> 2;   // 0..63
    int pix  = pix0 + pr;
    if (pix < HW) {
        int x = pix % DIMSZ;
        half8 v;
#pragma unroll
        for (int j = 0; j < 8; ++j) v[j] = (_Float16)tile[pr][h * 8 + j];
        half8* o8 = (half8*)out;
        if (role == 0) {
            if (x <= DIMSZ - 2) o8[(size_t)pix * 4 + h] = v;
        } else {
            if (x >= 1)         o8[(size_t)(pix - 1) * 4 + 2 + h] = v;
        }
    }
}

// ---------------------------------------------------------------------------
// Lines: (C, H) f32 -> (H, C) f32.  Tiny.
// ---------------------------------------------------------------------------
__global__ __launch_bounds__(256) void transpose_lines(
    const float* __restrict__ a, const float* __restrict__ b, const float* __restrict__ c,
    float* __restrict__ ta, float* __restrict__ tb, float* __restrict__ tc)
{
    const float* in  = (blockIdx.y == 0) ? a  : (blockIdx.y == 1) ? b  : c;
    float*       out = (blockIdx.y == 0) ? ta : (blockIdx.y == 1) ? tb : tc;
    for (int idx = threadIdx.x; idx < DIMSZ * CCH; idx += 256) {
        int p  = idx >> 4;
        int ch = idx & 15;
        out[idx] = in[ch * DIMSZ + p];
    }
}

// ---------------------------------------------------------------------------
// Per-plane main kernel. K = output slot (0: yz*x, 1: xz*y, 2: xy*z).
// One thread per (sample, q). Lane q loads 16-B chunk c = ((q&1)<<1)|(q>>1)
// of the 64-B pair-record at (row, ix0): lane holds pixel ix0+(q&1),
// channel-half (q>>1). Two loads per sample total (row iy0, row iy1),
// each one fully-used aligned 64-B L2 request.
// ---------------------------------------------------------------------------
template <int K>
__global__ __launch_bounds__(256) void td_plane(
    const float* __restrict__ coords_plane,
    const float* __restrict__ coords_line,
    const _Float16* __restrict__ ptex,
    const float* __restrict__ ltex,
    float* __restrict__ out)
{
    int gid = blockIdx.x * 256 + threadIdx.x;
    int i = gid >> 2;
    int q = gid & 3;
    if (i >= NPTS) return;

    // out_x uses plane coords slice 1 (yz), out_y slice 2 (xz), out_z slice 0 (xy)
    constexpr int PC = (K == 0) ? 1 : (K == 1) ? 2 : 0;

    const fvec2* cp = (const fvec2*)coords_plane;
    const fvec2* cl = (const fvec2*)coords_line;
    fvec2 g  = cp[(size_t)PC * NPTS + i];
    float gl = cl[(size_t)K * NPTS + i].y;   // lines use grid[:,1] (W==1)

    // ---- plane bilinear (W = H = 300) ----
    float ix = (g.x + 1.f) * 0.5f * (float)(DIMSZ - 1);
    float iy = (g.y + 1.f) * 0.5f * (float)(DIMSZ - 1);
    float ix0f = floorf(ix), iy0f = floorf(iy);
    float wx = ix - ix0f, wy = iy - iy0f;
    // gx,gy in [-1,1) => ix0 in [0,298]; clamps are safety no-ops
    int ix0 = min(max((int)ix0f, 0), DIMSZ - 2);
    int iy0 = min(max((int)iy0f, 0), DIMSZ - 1);
    int iy1 = min(iy0 + 1, DIMSZ - 1);

    const half8* t8 = (const half8*)ptex;
    int chunk = ((q & 1) << 1) | (q >> 1);
    half8 g0 = t8[((size_t)iy0 * DIMSZ + ix0) * 4 + chunk];
    half8 g1 = t8[((size_t)iy1 * DIMSZ + ix0) * 4 + chunk];

    fvec8 a0 = h2f8(g0);
    fvec8 a1 = h2f8(g1);
    fvec8 ty = a0 * (1.f - wy) + a1 * wy;      // y-lerp, in-lane

    // x-lerp: partner lane q^1 holds the other pixel, same channel-half
    fvec8 tu;
#pragma unroll
    for (int j = 0; j < 8; ++j) tu[j] = __shfl_xor(ty[j], 1);

    bool hiPix = (q & 1) != 0;   // this lane holds pixel ix0+1
    fvec8 fx = hiPix ? (tu * (1.f - wx) + ty * wx)
                     : (ty * (1.f - wx) + tu * wx);

    // lane q holds channel-half (q>>1); store needs quarter (q&1) of it
    fvec4 lo = {fx[0], fx[1], fx[2], fx[3]};
    fvec4 hi = {fx[4], fx[5], fx[6], fx[7]};
    fvec4 fq = (q & 1) ? hi : lo;

    // ---- line linear (H = 300), f32 (H,C): chunk q = channels q*4..q*4+3 ----
    float lyv = (gl + 1.f) * 0.5f * (float)(DIMSZ - 1);
    float ly0f = floorf(lyv);
    float wl = lyv - ly0f;
    int l0 = min(max((int)ly0f, 0), DIMSZ - 1);
    int l1 = min(l0 + 1, DIMSZ - 1);

    const fvec4* l4 = (const fvec4*)ltex;
    fvec4 u0 = l4[(size_t)l0 * 4 + q];
    fvec4 u1 = l4[(size_t)l1 * 4 + q];
    fvec4 fl = u0 * (1.f - wl) + u1 * wl;

    fvec4* out4 = (fvec4*)out;
    out4[(size_t)K * NPTS * 4 + (size_t)i * 4 + q] = fq * fl;
}

// ---------------------------------------------------------------------------
// Fallback (no usable ws): direct f32 gather from original (C,H,W) layout.
// ---------------------------------------------------------------------------
__global__ __launch_bounds__(256) void td_fallback(
    const float* __restrict__ coords_plane,
    const float* __restrict__ coords_line,
    const float* __restrict__ pxy, const float* __restrict__ pyz,
    const float* __restrict__ pxz,
    const float* __restrict__ lx, const float* __restrict__ ly,
    const float* __restrict__ lz,
    float* __restrict__ out)
{
    int gid = blockIdx.x * 256 + threadIdx.x;
    int i = gid >> 2;
    int q = gid & 3;
    if (i >= NPTS) return;

    const fvec2* cp = (const fvec2*)coords_plane;
    const fvec2* cl = (const fvec2*)coords_line;

    fvec4* out4 = (fvec4*)out;
    const float* planes[3] = {pyz, pxz, pxy};
    const float* lines[3]  = {lx, ly, lz};
    const int    pcs[3]    = {1, 2, 0};

#pragma unroll
    for (int k = 0; k < 3; ++k) {
        fvec2 g  = cp[(size_t)pcs[k] * NPTS + i];
        float gl = cl[(size_t)k * NPTS + i].y;

        float ix = (g.x + 1.f) * 0.5f * (float)(DIMSZ - 1);
        float iy = (g.y + 1.f) * 0.5f * (float)(DIMSZ - 1);
        float ix0f = floorf(ix), iy0f = floorf(iy);
        float wx = ix - ix0f, wy = iy - iy0f;
        int ix0 = min(max((int)ix0f, 0), DIMSZ - 1);
        int ix1 = min(ix0 + 1, DIMSZ - 1);
        int iy0 = min(max((int)iy0f, 0), DIMSZ - 1);
        int iy1 = min(iy0 + 1, DIMSZ - 1);
        float w00 = (1.f - wx) * (1.f - wy), w01 = wx * (1.f - wy);
        float w10 = (1.f - wx) * wy,         w11 = wx * wy;

        float lyv = (gl + 1.f) * 0.5f * (float)(DIMSZ - 1);
        float ly0f = floorf(lyv);
        float wl = lyv - ly0f;
        int l0 = min(max((int)ly0f, 0), DIMSZ - 1);
        int l1 = min(l0 + 1, DIMSZ - 1);

        const float* P = planes[k];
        const float* L = lines[k];
        size_t hw = (size_t)DIMSZ * DIMSZ;
        int b00 = iy0 * DIMSZ + ix0, b01 = iy0 * DIMSZ + ix1;
        int b10 = iy1 * DIMSZ + ix0, b11 = iy1 * DIMSZ + ix1;
        fvec4 r;
#pragma unroll
        for (int j = 0; j < 4; ++j) {
            size_t cb = (size_t)(q * 4 + j) * hw;
            float fp = P[cb + b00] * w00 + P[cb + b01] * w01 +
                       P[cb + b10] * w10 + P[cb + b11] * w11;
            size_t lb = (size_t)(q * 4 + j) * DIMSZ;
            float flv = L[lb + l0] * (1.f - wl) + L[lb + l1] * wl;
            r[j] = fp * flv;
        }
        out4[(size_t)k * NPTS * 4 + (size_t)i * 4 + q] = r;
    }
}

// ---------------------------------------------------------------------------
extern "C" void kernel_launch(void* const* d_in, const int* in_sizes, int n_in,
                              void* d_out, int out_size, void* d_ws, size_t ws_size,
                              hipStream_t stream)
{
    const float* coords_plane = (const float*)d_in[0];
    const float* coords_line  = (const float*)d_in[1];
    const float* pxy = (const float*)d_in[2];
    const float* pyz = (const float*)d_in[3];
    const float* pxz = (const float*)d_in[4];
    const float* lx  = (const float*)d_in[5];
    const float* ly  = (const float*)d_in[6];
    const float* lz  = (const float*)d_in[7];
    float* out = (float*)d_out;

    // replicated-pair plane: 300*300 records * 64 B = 5.76 MB (in halves: *32)
    const size_t planeH = (size_t)DIMSZ * DIMSZ * 32;   // _Float16 elements
    const size_t lineF  = (size_t)DIMSZ * CCH;          // floats per line
    const size_t needBytes = 3 * planeH * sizeof(_Float16) + 3 * lineF * sizeof(float);

    if (ws_size >= needBytes) {
        char* w = (char*)d_ws;
        _Float16* txy = (_Float16*)w;
        _Float16* tyz = txy + planeH;
        _Float16* txz = tyz + planeH;
        float* tlx = (float*)(w + 3 * planeH * sizeof(_Float16));
        float* tly = tlx + lineF;
        float* tlz = tly + lineF;

        dim3 gp((DIMSZ * DIMSZ + 63) / 64, 3);
        transpose_planes<<<gp, 256, 0, stream>>>(pxy, pyz, pxz, txy, tyz, txz);
        dim3 gl(1, 3);
        transpose_lines<<<gl, 256, 0, stream>>>(lx, ly, lz, tlx, tly, tlz);

        const int blocks = (NPTS * 4 + 255) / 256;
        td_plane<0><<<blocks, 256, 0, stream>>>(coords_plane, coords_line, tyz, tlx, out);
        td_plane<1><<<blocks, 256, 0, stream>>>(coords_plane, coords_line, txz, tly, out);
        td_plane<2><<<blocks, 256, 0, stream>>>(coords_plane, coords_line, txy, tlz, out);
    } else {
        const int blocks = (NPTS * 4 + 255) / 256;
        td_fallback<<<blocks, 256, 0, stream>>>(coords_plane, coords_line,
                                                pxy, pyz, pxz, lx, ly, lz, out);
    }
}

// Round 8
// 127.330 us; speedup vs baseline: 1.0549x; 1.0411x over previous
//
#include <hip/hip_runtime.h>

#define DIMSZ 300
#define CCH   16
#define NPTS  1048576
#define BLOCKS_PER_K 16384   // NPTS*4 / 256

typedef _Float16 half4 __attribute__((ext_vector_type(4)));
typedef float    fvec4 __attribute__((ext_vector_type(4)));
typedef float    fvec2 __attribute__((ext_vector_type(2)));

__device__ __forceinline__ fvec4 h2f(half4 h) {
    fvec4 r;
    r.x = (float)h[0]; r.y = (float)h[1]; r.z = (float)h[2]; r.w = (float)h[3];
    return r;
}

// ---------------------------------------------------------------------------
// Planes: (C, HW) f32  ->  (HW, C) fp16.  blockIdx.y selects which plane.
// (Exact R2 version — best measured config.)
// ---------------------------------------------------------------------------
__global__ __launch_bounds__(256) void transpose_planes(
    const float* __restrict__ a, const float* __restrict__ b, const float* __restrict__ c,
    _Float16* __restrict__ ta, _Float16* __restrict__ tb, _Float16* __restrict__ tc)
{
    const int HW = DIMSZ * DIMSZ;
    const float* in  = (blockIdx.y == 0) ? a  : (blockIdx.y == 1) ? b  : c;
    _Float16*    out = (blockIdx.y == 0) ? ta : (blockIdx.y == 1) ? tb : tc;

    __shared__ float tile[64][CCH + 1];
    int pix0 = blockIdx.x * 64;
    int t = threadIdx.x;

    int p  = t & 63;
    int cg = t >> 6;   // 0..3
#pragma unroll
    for (int k = 0; k < 4; ++k) {
        int ch  = cg * 4 + k;
        int pix = pix0 + p;
        tile[p][ch] = (pix < HW) ? in[(size_t)ch * HW + pix] : 0.f;
    }
    __syncthreads();

    int q  = t & 3;
    int pr = t >> 2;   // 0..63
    int pix = pix0 + pr;
    if (pix < HW) {
        half4 h;
        h[0] = (_Float16)tile[pr][q * 4 + 0];
        h[1] = (_Float16)tile[pr][q * 4 + 1];
        h[2] = (_Float16)tile[pr][q * 4 + 2];
        h[3] = (_Float16)tile[pr][q * 4 + 3];
        ((half4*)out)[(size_t)pix * 4 + q] = h;
    }
}

// ---------------------------------------------------------------------------
// Lines: (C, H) f32 -> (H, C) f32.  Tiny.
// ---------------------------------------------------------------------------
__global__ __launch_bounds__(256) void transpose_lines(
    const float* __restrict__ a, const float* __restrict__ b, const float* __restrict__ c,
    float* __restrict__ ta, float* __restrict__ tb, float* __restrict__ tc)
{
    const float* in  = (blockIdx.y == 0) ? a  : (blockIdx.y == 1) ? b  : c;
    float*       out = (blockIdx.y == 0) ? ta : (blockIdx.y == 1) ? tb : tc;
    for (int idx = threadIdx.x; idx < DIMSZ * CCH; idx += 256) {
        int p  = idx >> 4;
        int ch = idx & 15;
        out[idx] = in[ch * DIMSZ + p];
    }
}

// ---------------------------------------------------------------------------
// Clean fused main kernel: grid = 3*BLOCKS_PER_K; K = blockIdx.x >> 14, so
// all blocks of one plane dispatch before the next plane begins (per-XCD L2
// holds one 2.88 MB fp16 plane at a time). NO LDS staging, NO barrier, NO
// non-temporal hints — body identical to the best-measured R2 td_plane.
// Line texture (19.2 KB) read from global: L1-resident.
// One thread per (sample, channel-quad).
// ---------------------------------------------------------------------------
__global__ __launch_bounds__(256) void td_all(
    const float* __restrict__ coords_plane,
    const float* __restrict__ coords_line,
    const _Float16* __restrict__ tyz, const _Float16* __restrict__ txz,
    const _Float16* __restrict__ txy,
    const float* __restrict__ tlx, const float* __restrict__ tly,
    const float* __restrict__ tlz,
    float* __restrict__ out)
{
    const int K = blockIdx.x >> 14;           // 0,1,2
    const int b = blockIdx.x & (BLOCKS_PER_K - 1);

    const _Float16* ptex = (K == 0) ? tyz : (K == 1) ? txz : txy;
    const float*    ltex = (K == 0) ? tlx : (K == 1) ? tly : tlz;
    const int PC = (K == 0) ? 1 : (K == 1) ? 2 : 0;   // plane-coord slice

    int gid = b * 256 + threadIdx.x;
    int i = gid >> 2;
    int q = gid & 3;

    const fvec2* cp = (const fvec2*)coords_plane;
    const fvec2* cl = (const fvec2*)coords_line;
    fvec2 g  = cp[(size_t)PC * NPTS + i];
    float gl = cl[(size_t)K * NPTS + i].y;    // lines use grid[:,1] (W==1)

    // ---- plane bilinear (W = H = 300) ----
    float ix = (g.x + 1.f) * 0.5f * (float)(DIMSZ - 1);
    float iy = (g.y + 1.f) * 0.5f * (float)(DIMSZ - 1);
    float ix0f = floorf(ix), iy0f = floorf(iy);
    float wx = ix - ix0f, wy = iy - iy0f;
    int ix0 = min(max((int)ix0f, 0), DIMSZ - 1);
    int ix1 = min(ix0 + 1, DIMSZ - 1);
    int iy0 = min(max((int)iy0f, 0), DIMSZ - 1);
    int iy1 = min(iy0 + 1, DIMSZ - 1);

    const half4* t4 = (const half4*)ptex;
    size_t r0 = (size_t)iy0 * DIMSZ;
    size_t r1 = (size_t)iy1 * DIMSZ;
    fvec4 v00 = h2f(t4[(r0 + ix0) * 4 + q]);
    fvec4 v01 = h2f(t4[(r0 + ix1) * 4 + q]);
    fvec4 v10 = h2f(t4[(r1 + ix0) * 4 + q]);
    fvec4 v11 = h2f(t4[(r1 + ix1) * 4 + q]);

    float w00 = (1.f - wx) * (1.f - wy);
    float w01 = wx * (1.f - wy);
    float w10 = (1.f - wx) * wy;
    float w11 = wx * wy;

    fvec4 f = v00 * w00 + v01 * w01 + v10 * w10 + v11 * w11;

    // ---- line linear (H = 300), L1-resident ----
    float lyv = (gl + 1.f) * 0.5f * (float)(DIMSZ - 1);
    float ly0f = floorf(lyv);
    float wl = lyv - ly0f;
    int l0 = min(max((int)ly0f, 0), DIMSZ - 1);
    int l1 = min(l0 + 1, DIMSZ - 1);

    const fvec4* l4 = (const fvec4*)ltex;
    fvec4 u0 = l4[(size_t)l0 * 4 + q];
    fvec4 u1 = l4[(size_t)l1 * 4 + q];
    fvec4 fl = u0 * (1.f - wl) + u1 * wl;

    fvec4* out4 = (fvec4*)out;
    out4[(size_t)K * NPTS * 4 + (size_t)i * 4 + q] = f * fl;
}

// ---------------------------------------------------------------------------
// Fallback (no usable ws): direct f32 gather from original (C,H,W) layout.
// ---------------------------------------------------------------------------
__global__ __launch_bounds__(256) void td_fallback(
    const float* __restrict__ coords_plane,
    const float* __restrict__ coords_line,
    const float* __restrict__ pxy, const float* __restrict__ pyz,
    const float* __restrict__ pxz,
    const float* __restrict__ lx, const float* __restrict__ ly,
    const float* __restrict__ lz,
    float* __restrict__ out)
{
    int gid = blockIdx.x * 256 + threadIdx.x;
    int i = gid >> 2;
    int q = gid & 3;
    if (i >= NPTS) return;

    const fvec2* cp = (const fvec2*)coords_plane;
    const fvec2* cl = (const fvec2*)coords_line;

    fvec4* out4 = (fvec4*)out;
    const float* planes[3] = {pyz, pxz, pxy};
    const float* lines[3]  = {lx, ly, lz};
    const int    pcs[3]    = {1, 2, 0};

#pragma unroll
    for (int k = 0; k < 3; ++k) {
        fvec2 g  = cp[(size_t)pcs[k] * NPTS + i];
        float gl = cl[(size_t)k * NPTS + i].y;

        float ix = (g.x + 1.f) * 0.5f * (float)(DIMSZ - 1);
        float iy = (g.y + 1.f) * 0.5f * (float)(DIMSZ - 1);
        float ix0f = floorf(ix), iy0f = floorf(iy);
        float wx = ix - ix0f, wy = iy - iy0f;
        int ix0 = min(max((int)ix0f, 0), DIMSZ - 1);
        int ix1 = min(ix0 + 1, DIMSZ - 1);
        int iy0 = min(max((int)iy0f, 0), DIMSZ - 1);
        int iy1 = min(iy0 + 1, DIMSZ - 1);
        float w00 = (1.f - wx) * (1.f - wy), w01 = wx * (1.f - wy);
        float w10 = (1.f - wx) * wy,         w11 = wx * wy;

        float lyv = (gl + 1.f) * 0.5f * (float)(DIMSZ - 1);
        float ly0f = floorf(lyv);
        float wl = lyv - ly0f;
        int l0 = min(max((int)ly0f, 0), DIMSZ - 1);
        int l1 = min(l0 + 1, DIMSZ - 1);

        const float* P = planes[k];
        const float* L = lines[k];
        size_t hw = (size_t)DIMSZ * DIMSZ;
        int b00 = iy0 * DIMSZ + ix0, b01 = iy0 * DIMSZ + ix1;
        int b10 = iy1 * DIMSZ + ix0, b11 = iy1 * DIMSZ + ix1;
        fvec4 r;
#pragma unroll
        for (int j = 0; j < 4; ++j) {
            size_t cb = (size_t)(q * 4 + j) * hw;
            float fp = P[cb + b00] * w00 + P[cb + b01] * w01 +
                       P[cb + b10] * w10 + P[cb + b11] * w11;
            size_t lb = (size_t)(q * 4 + j) * DIMSZ;
            float flv = L[lb + l0] * (1.f - wl) + L[lb + l1] * wl;
            r[j] = fp * flv;
        }
        out4[(size_t)k * NPTS * 4 + (size_t)i * 4 + q] = r;
    }
}

// ---------------------------------------------------------------------------
extern "C" void kernel_launch(void* const* d_in, const int* in_sizes, int n_in,
                              void* d_out, int out_size, void* d_ws, size_t ws_size,
                              hipStream_t stream)
{
    const float* coords_plane = (const float*)d_in[0];
    const float* coords_line  = (const float*)d_in[1];
    const float* pxy = (const float*)d_in[2];
    const float* pyz = (const float*)d_in[3];
    const float* pxz = (const float*)d_in[4];
    const float* lx  = (const float*)d_in[5];
    const float* ly  = (const float*)d_in[6];
    const float* lz  = (const float*)d_in[7];
    float* out = (float*)d_out;

    const size_t planeH = (size_t)DIMSZ * DIMSZ * CCH;   // halves per plane
    const size_t lineF  = (size_t)DIMSZ * CCH;           // floats per line
    const size_t needBytes = 3 * planeH * sizeof(_Float16) + 3 * lineF * sizeof(float);

    if (ws_size >= needBytes) {
        char* w = (char*)d_ws;
        _Float16* txy = (_Float16*)w;
        _Float16* tyz = txy + planeH;
        _Float16* txz = tyz + planeH;
        float* tlx = (float*)(w + 3 * planeH * sizeof(_Float16));
        float* tly = tlx + lineF;
        float* tlz = tly + lineF;

        dim3 gp((DIMSZ * DIMSZ + 63) / 64, 3);
        transpose_planes<<<gp, 256, 0, stream>>>(pxy, pyz, pxz, txy, tyz, txz);
        dim3 gl(1, 3);
        transpose_lines<<<gl, 256, 0, stream>>>(lx, ly, lz, tlx, tly, tlz);

        td_all<<<3 * BLOCKS_PER_K, 256, 0, stream>>>(coords_plane, coords_line,
                                                     tyz, txz, txy, tlx, tly, tlz, out);
    } else {
        const int blocks = (NPTS * 4 + 255) / 256;
        td_fallback<<<blocks, 256, 0, stream>>>(coords_plane, coords_line,
                                                pxy, pyz, pxz, lx, ly, lz, out);
    }
}